// Round 9
// baseline (2757.875 us; speedup 1.0000x reference)
//
#include <hip/hip_runtime.h>
#include <math.h>

#define B_ 1024
#define T_ 128
#define H_ 2048
#define C_ 10

typedef __bf16 bf16_t;
typedef __bf16 bf16x8 __attribute__((ext_vector_type(8)));
typedef __bf16 bf16x4 __attribute__((ext_vector_type(4)));
typedef float f32x4 __attribute__((ext_vector_type(4)));

// Static device storage: bf16 h ping-pong (8 MB), bf16 W_hh^T (8 MB),
// per-(t,bm) readiness counters (XCD-local handoff).
__device__ __align__(16) bf16_t g_hb[2][(size_t)B_ * H_];
__device__ __align__(16) bf16_t g_whhT[(size_t)H_ * H_];
__device__ int g_cnt[T_ * 8];   // [t][bm]; t=0 seeded to 32 by rnn_init

// AUX: cache policy. 0 = default; 1 = sc0 (force L1 miss -> read XCD L2).
template <int AUX>
__device__ __forceinline__ void gload16(const bf16_t* g, bf16_t* l) {
    __builtin_amdgcn_global_load_lds(
        (const __attribute__((address_space(1))) void*)g,
        (__attribute__((address_space(3))) void*)l, 16, 0, AUX);
}

// Counted-vmcnt barrier: retire oldest pipeline stage without draining.
template <int VM>
__device__ __forceinline__ void wait_vm_barrier() {
    asm volatile("s_waitcnt vmcnt(%0)\n\ts_barrier" :: "n"(VM) : "memory");
}

// One-time: W_hhT[n][k] = bf16(W_hh[k][n]) — B operand must be K-contiguous.
__global__ __launch_bounds__(256) void prep_whhT(const float* __restrict__ Whh) {
    __shared__ float tile[32][33];
    const int i  = threadIdx.x >> 3;
    const int j4 = (threadIdx.x & 7) * 4;
    const int r0 = blockIdx.y * 32;
    const int c0 = blockIdx.x * 32;
    f32x4 v = *(const f32x4*)(Whh + (size_t)(r0 + i) * H_ + c0 + j4);
    tile[i][j4 + 0] = v[0]; tile[i][j4 + 1] = v[1];
    tile[i][j4 + 2] = v[2]; tile[i][j4 + 3] = v[3];
    __syncthreads();
    bf16x4 o;
#pragma unroll
    for (int r = 0; r < 4; ++r) o[r] = (bf16_t)tile[j4 + r][i];
    *(bf16x4*)&g_whhT[(size_t)(c0 + i) * H_ + r0 + j4] = o;
}

// t = 0: h = tanh(x[:,0]*W_hx + b_h); also (re)initialize the counters.
__global__ __launch_bounds__(256) void rnn_init(const float* __restrict__ x,
                                                const float* __restrict__ Whx,
                                                const float* __restrict__ bh) {
    if (blockIdx.x == 0) {
        for (int i = threadIdx.x; i < T_ * 8; i += 256)
            g_cnt[i] = (i < 8) ? 32 : 0;   // g_cnt[0][*] = 32 (h0 ready)
    }
    const int gid = blockIdx.x * 256 + threadIdx.x;
    const int row = gid >> 9;
    const int col = (gid & 511) << 2;
    const float xv = x[(size_t)row * T_];
    f32x4 w = *(const f32x4*)&Whx[col];
    f32x4 b = *(const f32x4*)&bh[col];
    bf16x4 o;
#pragma unroll
    for (int j = 0; j < 4; ++j) o[j] = (bf16_t)tanhf(fmaf(xv, w[j], b[j]));
    *(bf16x4*)&g_hb[0][(size_t)row * H_ + col] = o;
}

// Persistent RNN. v9 = v7 (proven 2192 us) at 4 waves/SIMD:
// 1024 threads = 16 waves = 4 mn-groups (2Mx2N, v7's 64x32 wave tile,
// same acc[4][2]) x 4 K-quarters (kh computes chunk-pairs p == kh mod 4).
// Round-robin wave->SIMD puts kh 0..3 of one mn-group on each SIMD ->
// exactly ONE computing wave per SIMD per iter (32 MFMA + 24 ds_read_b128),
// three waves covering staging/waits. Traffic per CU per step unchanged
// vs v7 (MFMA 2048, frag reads 1.57 MB, DMA 768 KB); barrier count
// unchanged (16/step). Staging uniform: per pair per thread A,A,B (1024
// threads), steady vmcnt(3), 3 pair-slots (A 32 KB + B 16 KB each,
// 144 KB total). Additions: 4-way K-reduce in conflict-free b128 fragment
// layout (aliased into dead slots; write-side vmcnt(0) + barriers on both
// sides) and 4-way-split epilogue.
__global__ __launch_bounds__(1024, 4) void rnn_persist(const float* __restrict__ x,
                                                       const float* __restrict__ Whx,
                                                       const float* __restrict__ bh) {
    extern __shared__ __align__(16) bf16_t smem[];
    bf16_t* As = smem;                 // 3 pair-slots x 16384 elems (32 KB)
    bf16_t* Bs = smem + 3 * 16384;     // 3 pair-slots x 8192 elems (16 KB)
    float*  red = (float*)smem;        // reduce scratch aliases slots (dead)

    const int tid  = threadIdx.x;
    const int lane = tid & 63;
    const int wave = tid >> 6;                       // 0..15
    const int mn   = wave & 3;                       // SIMD-mate group
    const int kh   = wave >> 2;                      // K-quarter 0..3
    const int li  = blockIdx.x;
    const int bm  = li & 7;                          // == XCD (blk%8 map)
    const int bn  = li >> 3;                         // 0..31

    const int wm = (mn & 1) * 64;                    // M band (64 rows)
    const int wn = (mn >> 1) * 32;                   // N band (32 cols)
    const int fr = lane & 15, fq = lane >> 4;

    // Staging: A chunk = 8192 elems = 1 load/thread; linear index tid
    // holds row tid>>3, lds-chunk tid&7; global chunk = (tid&7)^(row&7).
    const int rA = tid >> 3;                         // 0..127
    const int cg = (tid & 7) ^ (rA & 7);
    const size_t aofsg = (size_t)(bm * 128 + rA) * H_ + cg * 8;
    // B pair = 8192 elems = 1 load/thread; tid<512 stages the pair's even
    // chunk (rows 0..63), tid>=512 the odd chunk.
    const int rB = (tid >> 3) & 63;
    const int bhalf = tid >> 9;
    const bf16_t* const gb0 = g_whhT + (size_t)(bn * 64 + rB) * H_ + cg * 8;

#define ISSUE_A(PS, Q)                                                   \
    do {                                                                 \
        gload16<1>(gpa, As + (PS) * 16384 + (Q) * 8192 + tid * 8);       \
        gpa += kstep;                                                    \
    } while (0)
#define ISSUE_B(PS)                                                      \
    do {                                                                 \
        gload16<0>(gpb, Bs + (PS) * 8192 + tid * 8);                     \
        gpb += kstep2;                                                   \
    } while (0)

    // frag offsets (elems): row*64 + ((cc*4+fq) ^ (row&7))*8; row&7 == fr&7.
    const int xr0 = (fq ^ (fr & 7)) * 8;
    const int xr1 = ((4 + fq) ^ (fr & 7)) * 8;
    int aoff[4][2], boff[2][2];
#pragma unroll
    for (int i = 0; i < 4; ++i) {
        aoff[i][0] = (wm + i * 16 + fr) * 64 + xr0;
        aoff[i][1] = (wm + i * 16 + fr) * 64 + xr1;
    }
#pragma unroll
    for (int j = 0; j < 2; ++j) {
        boff[j][0] = (wn + j * 16 + fr) * 64 + xr0;
        boff[j][1] = (wn + j * 16 + fr) * 64 + xr1;
    }

    f32x4 acc[4][2];

    // One pair = 2 chunks (q=0,1) = 32 MFMA + 24 ds_read_b128.
#define COMPUTE_PAIR(PS)                                                    \
    {                                                                       \
        _Pragma("unroll")                                                   \
        for (int q = 0; q < 2; ++q) {                                       \
            const bf16_t* Ab = As + (PS) * 16384 + q * 8192;                \
            const bf16_t* Bb = Bs + (PS) * 8192 + q * 4096;                 \
            _Pragma("unroll")                                               \
            for (int cc = 0; cc < 2; ++cc) {                                \
                bf16x8 af[4], bfv[2];                                       \
                _Pragma("unroll")                                           \
                for (int j = 0; j < 2; ++j)                                 \
                    bfv[j] = *(const bf16x8*)(Bb + boff[j][cc]);            \
                _Pragma("unroll")                                           \
                for (int i = 0; i < 4; ++i)                                 \
                    af[i] = *(const bf16x8*)(Ab + aoff[i][cc]);             \
                _Pragma("unroll")                                           \
                for (int i = 0; i < 4; ++i)                                 \
                    _Pragma("unroll")                                       \
                    for (int j = 0; j < 2; ++j)                             \
                        acc[i][j] = __builtin_amdgcn_mfma_f32_16x16x32_bf16(\
                            af[i], bfv[j], acc[i][j], 0, 0, 0);             \
            }                                                               \
        }                                                                   \
    }

    // Iter p (steady): retire pair p ({A,A,B} counted), stage pair p+2,
    // compute pair p iff its K-quarter matches this wave.
#define ITR(P, V, SS)                                                       \
    do {                                                                    \
        wait_vm_barrier<V>();                                               \
        ISSUE_A(SS, 0); ISSUE_A(SS, 1); ISSUE_B(SS);                        \
        if (kh == ((P) & 3)) COMPUTE_PAIR((P) % 3);                         \
    } while (0)

    // epilogue constants (step-invariant)
    float wv[2], bv[2];
#pragma unroll
    for (int j = 0; j < 2; ++j) {
        const int col = bn * 64 + wn + j * 16 + fr;
        wv[j] = Whx[col];
        bv[j] = bh[col];
    }

    // reduce layout: [mn][i-block][src kh][j] x lane f32x4 (b128/lane).
#define RIDX(I, SRC, J) (((((mn * 4 + (I)) * 4 + (SRC)) * 2 + (J)) * 256) + lane * 4)

#pragma unroll 1
    for (int t = 1; t < T_; ++t) {
        const bf16_t* __restrict__ Abuf = g_hb[(t - 1) & 1];
        bf16_t* __restrict__ hn = g_hb[t & 1];
        // zig-zag: odd steps walk K from the top -- L2 still holds that tail
        const int koff   = (t & 1) ? (H_ - 64) : 0;
        const int kstep  = (t & 1) ? -64 : 64;
        const int kstep2 = 2 * kstep;
        const bf16_t* gpa = Abuf + aofsg + koff;
        const bf16_t* gpb = gb0 + koff + bhalf * kstep;

        // B is immutable: stage pairs 0,1 BEFORE the dependency wait.
        ISSUE_B(0); ISSUE_B(1);

        // wait until all 32 same-XCD writers of h-rows bm finished step t-1
        if (tid == 0) {
            while (__hip_atomic_load(&g_cnt[(t - 1) * 8 + bm], __ATOMIC_RELAXED,
                                     __HIP_MEMORY_SCOPE_AGENT) != 32)
                __builtin_amdgcn_s_sleep(2);
        }
        // raw barrier: keeps the B prefetch alive (no vmcnt(0) drain);
        // sc0 A-loads read the fresh XCD L2 (v7-proven pattern).
        asm volatile("s_barrier" ::: "memory");

        ISSUE_A(0, 0); ISSUE_A(0, 1); ISSUE_A(1, 0); ISSUE_A(1, 1);

#pragma unroll
        for (int i = 0; i < 4; ++i)
#pragma unroll
            for (int j = 0; j < 2; ++j) acc[i][j] = (f32x4)(0.f);

        // 16 pairs, 3 pair-slots, 2 pairs in flight, steady vmcnt(3).
        // Queue/thread at iter0: [B0,B1,A00,A01,A10,A11] -> vmcnt(2)
        // retires {B0,B1,A00,A01}; steady vmcnt(3) retires one {A,A,B}.
        ITR(0, 2, 2);  ITR(1, 3, 0);  ITR(2, 3, 1);  ITR(3, 3, 2);
        ITR(4, 3, 0);  ITR(5, 3, 1);  ITR(6, 3, 2);  ITR(7, 3, 0);
        ITR(8, 3, 1);  ITR(9, 3, 2);  ITR(10, 3, 0); ITR(11, 3, 1);
        ITR(12, 3, 2); ITR(13, 3, 0);                 // ITR(13) stages pair 15
        wait_vm_barrier<3>(); if (kh == 2) COMPUTE_PAIR(2);   // iter 14
        wait_vm_barrier<0>(); if (kh == 3) COMPUTE_PAIR(0);   // iter 15

        // ---- 4-way K-quarter reduce. All DMA retired (vmcnt(0) above);
        // barrier both sides; red aliases the (now dead) slots.
        __syncthreads();
        {
#pragma unroll
            for (int i = 0; i < 4; ++i)
                if (i != kh) {
                    *(f32x4*)&red[RIDX(i, kh, 0)] = acc[i][0];
                    *(f32x4*)&red[RIDX(i, kh, 1)] = acc[i][1];
                }
        }
        __syncthreads();

        // finish own i-block (= kh): add 3 partials, then epilogue.
#define FIN(K)                                                              \
        {                                                                   \
            _Pragma("unroll")                                               \
            for (int src = 0; src < 4; ++src)                               \
                if (src != (K)) {                                           \
                    acc[K][0] += *(const f32x4*)&red[RIDX(K, src, 0)];      \
                    acc[K][1] += *(const f32x4*)&red[RIDX(K, src, 1)];      \
                }                                                           \
            const int row0 = bm * 128 + wm + (K) * 16 + fq * 4;             \
            float xv[4];                                                    \
            _Pragma("unroll")                                               \
            for (int r = 0; r < 4; ++r) xv[r] = x[(row0 + r) * T_ + t];     \
            _Pragma("unroll")                                               \
            for (int j = 0; j < 2; ++j) {                                   \
                const int col = bn * 64 + wn + j * 16 + fr;                 \
                _Pragma("unroll")                                           \
                for (int r = 0; r < 4; ++r)                                 \
                    hn[(size_t)(row0 + r) * H_ + col] =                     \
                        (bf16_t)tanhf(acc[K][j][r] + xv[r] * wv[j] + bv[j]);\
            }                                                               \
        }
        if (kh == 0)      FIN(0)
        else if (kh == 1) FIN(1)
        else if (kh == 2) FIN(2)
        else              FIN(3)
#undef FIN

        // publish: drain this wave's stores to L2, join waves, bump counter.
        asm volatile("s_waitcnt vmcnt(0)" ::: "memory");
        __syncthreads();
        if (tid == 0)
            __hip_atomic_fetch_add(&g_cnt[t * 8 + bm], 1, __ATOMIC_RELAXED,
                                   __HIP_MEMORY_SCOPE_AGENT);
    }
#undef RIDX
#undef ITR
#undef COMPUTE_PAIR
#undef ISSUE_B
#undef ISSUE_A
}

// p = h_T @ W_ph + b_p : one wave per batch row, fp32 accumulate.
__global__ __launch_bounds__(64) void rnn_proj(const float* __restrict__ Wph,
                                               const float* __restrict__ bp,
                                               float* __restrict__ out, int sb) {
    const int b = blockIdx.x;
    const int l = threadIdx.x;
    const bf16_t* h = g_hb[sb] + (size_t)b * H_;
    float acc[C_];
#pragma unroll
    for (int c = 0; c < C_; ++c) acc[c] = 0.f;
    for (int k = l; k < H_; k += 64) {
        const float hv = (float)h[k];
#pragma unroll
        for (int c = 0; c < C_; ++c)
            acc[c] = fmaf(hv, Wph[k * C_ + c], acc[c]);
    }
#pragma unroll
    for (int off = 32; off > 0; off >>= 1)
#pragma unroll
        for (int c = 0; c < C_; ++c) acc[c] += __shfl_down(acc[c], off);
    if (l == 0) {
#pragma unroll
        for (int c = 0; c < C_; ++c) out[b * C_ + c] = acc[c] + bp[c];
    }
}

extern "C" void kernel_launch(void* const* d_in, const int* in_sizes, int n_in,
                              void* d_out, int out_size, void* d_ws, size_t ws_size,
                              hipStream_t stream) {
    const float* x   = (const float*)d_in[0];   // [1024,128]
    const float* Whx = (const float*)d_in[1];   // [1,2048]
    const float* Whh = (const float*)d_in[2];   // [2048,2048]
    const float* bh  = (const float*)d_in[3];   // [2048]
    const float* Wph = (const float*)d_in[4];   // [2048,10]
    const float* bp  = (const float*)d_in[5];   // [1,10]
    float* out = (float*)d_out;                 // [1024,10]

    static bool attr_set = false;
    if (!attr_set) {
        hipFuncSetAttribute((const void*)rnn_persist,
                            hipFuncAttributeMaxDynamicSharedMemorySize, 147456);
        attr_set = true;
    }

    prep_whhT<<<dim3(64, 64), 256, 0, stream>>>(Whh);
    rnn_init<<<(B_ * H_ / 4) / 256, 256, 0, stream>>>(x, Whx, bh);
    rnn_persist<<<256, 1024, 147456, stream>>>(x, Whx, bh);
    rnn_proj<<<B_, 64, 0, stream>>>(Wph, bp, out, (T_ - 1) & 1);
}

// Round 10
// 2261.817 us; speedup vs baseline: 1.2193x; 1.2193x over previous
//
#include <hip/hip_runtime.h>
#include <math.h>

#define B_ 1024
#define T_ 128
#define H_ 2048
#define C_ 10

typedef __bf16 bf16_t;
typedef __bf16 bf16x8 __attribute__((ext_vector_type(8)));
typedef __bf16 bf16x4 __attribute__((ext_vector_type(4)));
typedef float f32x4 __attribute__((ext_vector_type(4)));

// Static device storage: bf16 h ping-pong (8 MB), bf16 W_hh^T (8 MB),
// per-(t,mtile) readiness counters (XCD-local handoff; mtile = 64 rows).
__device__ __align__(16) bf16_t g_hb[2][(size_t)B_ * H_];
__device__ __align__(16) bf16_t g_whhT[(size_t)H_ * H_];
__device__ int g_cnt[T_ * 16];  // [t][mtile]; t=0 seeded to 16 by rnn_init

// AUX: cache policy. 0 = default; 1 = sc0 (force L1 miss -> read XCD L2).
template <int AUX>
__device__ __forceinline__ void gload16(const bf16_t* g, bf16_t* l) {
    __builtin_amdgcn_global_load_lds(
        (const __attribute__((address_space(1))) void*)g,
        (__attribute__((address_space(3))) void*)l, 16, 0, AUX);
}

// Counted-vmcnt barrier: retire oldest pipeline stage without draining.
template <int VM>
__device__ __forceinline__ void wait_vm_barrier() {
    asm volatile("s_waitcnt vmcnt(%0)\n\ts_barrier" :: "n"(VM) : "memory");
}

// One-time: W_hhT[n][k] = bf16(W_hh[k][n]) — B operand must be K-contiguous.
__global__ __launch_bounds__(256) void prep_whhT(const float* __restrict__ Whh) {
    __shared__ float tile[32][33];
    const int i  = threadIdx.x >> 3;
    const int j4 = (threadIdx.x & 7) * 4;
    const int r0 = blockIdx.y * 32;
    const int c0 = blockIdx.x * 32;
    f32x4 v = *(const f32x4*)(Whh + (size_t)(r0 + i) * H_ + c0 + j4);
    tile[i][j4 + 0] = v[0]; tile[i][j4 + 1] = v[1];
    tile[i][j4 + 2] = v[2]; tile[i][j4 + 3] = v[3];
    __syncthreads();
    bf16x4 o;
#pragma unroll
    for (int r = 0; r < 4; ++r) o[r] = (bf16_t)tile[j4 + r][i];
    *(bf16x4*)&g_whhT[(size_t)(c0 + i) * H_ + r0 + j4] = o;
}

// t = 0: h = tanh(x[:,0]*W_hx + b_h); also (re)initialize the counters.
__global__ __launch_bounds__(256) void rnn_init(const float* __restrict__ x,
                                                const float* __restrict__ Whx,
                                                const float* __restrict__ bh) {
    if (blockIdx.x == 0) {
        for (int i = threadIdx.x; i < T_ * 16; i += 256)
            g_cnt[i] = (i < 16) ? 16 : 0;   // g_cnt[0][*] = 16 (h0 ready)
    }
    const int gid = blockIdx.x * 256 + threadIdx.x;
    const int row = gid >> 9;
    const int col = (gid & 511) << 2;
    const float xv = x[(size_t)row * T_];
    f32x4 w = *(const f32x4*)&Whx[col];
    f32x4 b = *(const f32x4*)&bh[col];
    bf16x4 o;
#pragma unroll
    for (int j = 0; j < 4; ++j) o[j] = (bf16_t)tanhf(fmaf(xv, w[j], b[j]));
    *(bf16x4*)&g_hb[0][(size_t)row * H_ + col] = o;
}

// Persistent RNN. v10 = v7's proven discipline (6-slot ring, 3 loads per
// chunk per thread, steady vmcnt(6), 16 super-iters, zig-zag, sc0-A,
// XCD-local rendezvous) with a J-fat retile that cuts LDS frag reads 33%:
//  - block tile 64x128 (16 M-tiles x 16 N-tiles = 256 blocks);
//  - 8 waves = 2 N-halves x 4 K-quarters; wave tile 64x64, acc[4][4]:
//    frag reads/MFMA = (4+4)/(4*4) = 0.5 vs v7's 0.75;
//  - per super-iter (2 chunks) exactly ONE wave per SIMD computes 32 MFMA
//    (wave w & w+4 alternate) -> all SIMDs busy every iter (v9's flaw) and
//    2 waves/SIMD hide each other's stalls (v7's win);
//  - rendezvous per 64-row M-tile: 16 same-XCD writers;
//  - 4-way K-reduce in conflict-free b128 fragment layout, 96 KB aliased
//    into the dead ring (extra barrier guards slot-0/1 overlap with u15);
//  - T5 setprio(1) around the MFMA cluster.
__global__ __launch_bounds__(512, 1) void rnn_persist(const float* __restrict__ x,
                                                      const float* __restrict__ Whx,
                                                      const float* __restrict__ bh) {
    extern __shared__ __align__(16) bf16_t smem[];
    bf16_t* As = smem;                 // 6 slots x 4096 elems (8 KB) = 48 KB
    bf16_t* Bs = smem + 6 * 4096;      // 6 slots x 8192 elems (16 KB) = 96 KB
    float*  red = (float*)smem;        // 96 KB reduce scratch (slots dead)

    const int tid  = threadIdx.x;
    const int lane = tid & 63;
    const int wave = tid >> 6;                       // 0..7
    const int nh   = wave & 1;                       // N half (64 cols)
    const int kh   = wave >> 1;                      // K quarter (chunk&3)
    const int li  = blockIdx.x;
    const int bm8 = li & 7;                          // XCD (blk%8 map)
    const int mtile = bm8 * 2 + ((li >> 3) & 1);     // rows [mtile*64,+64)
    const int bn  = li >> 4;                         // 0..15 (128-col tile)

    const int fr = lane & 15, fq = lane >> 4;

    // Staging: linear index tid holds row tid>>3, lds-chunk tid&7;
    // global k-chunk = (tid&7) ^ (row&7)  (8-row spread, v7-proven).
    const int rA = tid >> 3;                         // 0..63
    const int cg = (tid & 7) ^ (rA & 7);
    const size_t aofsg = (size_t)(mtile * 64 + rA) * H_ + cg * 8;
    const bf16_t* const gb0 = g_whhT + (size_t)(bn * 128 + rA) * H_ + cg * 8;

    // A chunk = 64 rows x 64 k = 8 KB (1 load/thread); B chunk = 128 cols
    // x 64 k = 16 KB (2 loads/thread: cols 0..63, 64..127).
#define ISSUE_A(S)                                                       \
    do {                                                                 \
        gload16<1>(gpa, As + (S) * 4096 + tid * 8);                      \
        gpa += kstep;                                                    \
    } while (0)
#define ISSUE_B(S)                                                       \
    do {                                                                 \
        gload16<0>(gpb,           Bs + (S) * 8192 + tid * 8);            \
        gload16<0>(gpb + 64 * H_, Bs + (S) * 8192 + 4096 + tid * 8);     \
        gpb += kstep;                                                    \
    } while (0)
#define ISSUE_AB(S) do { ISSUE_A(S); ISSUE_B(S); } while (0)

    // frag offsets: addr = row*64 + ((cc*4+fq) ^ (row&7))*8; row&7 == fr&7.
    const int xr0 = (fq ^ (fr & 7)) * 8;
    const int xr1 = ((4 + fq) ^ (fr & 7)) * 8;
    int aoff[4][2], boff[4][2];
#pragma unroll
    for (int i = 0; i < 4; ++i) {
        aoff[i][0] = (i * 16 + fr) * 64 + xr0;
        aoff[i][1] = (i * 16 + fr) * 64 + xr1;
    }
#pragma unroll
    for (int j = 0; j < 4; ++j) {
        boff[j][0] = (nh * 64 + j * 16 + fr) * 64 + xr0;
        boff[j][1] = (nh * 64 + j * 16 + fr) * 64 + xr1;
    }

    f32x4 acc[4][4];

    // One chunk: 16 ds_read_b128 + 32 MFMA (reads/MFMA = 0.5).
#define COMPUTE(SLOT)                                                       \
    {                                                                       \
        __builtin_amdgcn_s_setprio(1);                                      \
        _Pragma("unroll")                                                   \
        for (int cc = 0; cc < 2; ++cc) {                                    \
            bf16x8 af[4], bfv[4];                                           \
            _Pragma("unroll")                                               \
            for (int j = 0; j < 4; ++j)                                     \
                bfv[j] = *(const bf16x8*)(Bs + (SLOT) * 8192 + boff[j][cc]);\
            _Pragma("unroll")                                               \
            for (int i = 0; i < 4; ++i)                                     \
                af[i] = *(const bf16x8*)(As + (SLOT) * 4096 + aoff[i][cc]); \
            _Pragma("unroll")                                               \
            for (int i = 0; i < 4; ++i)                                     \
                _Pragma("unroll")                                           \
                for (int j = 0; j < 4; ++j)                                 \
                    acc[i][j] = __builtin_amdgcn_mfma_f32_16x16x32_bf16(    \
                        af[i], bfv[j], acc[i][j], 0, 0, 0);                 \
        }                                                                   \
        __builtin_amdgcn_s_setprio(0);                                      \
    }

    // Super-iter U: wait (retire chunk pair 2U,2U+1), stage pair 2U+4,
    // compute own-parity chunk. Chunks 2U,2U+1 have parities {0,1} or
    // {2,3}: waves kh 0,1 compute on even U, kh 2,3 on odd U -> exactly
    // one computing wave per SIMD per super-iter.
#define ITR(U, V)                                                           \
    do {                                                                    \
        wait_vm_barrier<V>();                                               \
        ISSUE_AB((2 * (U) + 4) % 6); ISSUE_AB((2 * (U) + 5) % 6);           \
        if (kh == ((2 * (U)) & 3)) COMPUTE((2 * (U)) % 6)                   \
        else if (kh == ((2 * (U) + 1) & 3)) COMPUTE((2 * (U) + 1) % 6)      \
    } while (0)

    // epilogue constants (step-invariant)
    float wv[4], bv[4];
#pragma unroll
    for (int j = 0; j < 4; ++j) {
        const int col = bn * 128 + nh * 64 + j * 16 + fr;
        wv[j] = Whx[col];
        bv[j] = bh[col];
    }

    // reduce region: (nh, i-block, writer-slot w2 in 0..2, j) x lane f32x4.
#define RIDX(I, W, J) \
    (((((nh * 4 + (I)) * 3 + (W)) * 4 + (J)) * 256) + lane * 4)

#pragma unroll 1
    for (int t = 1; t < T_; ++t) {
        const bf16_t* __restrict__ Abuf = g_hb[(t - 1) & 1];
        bf16_t* __restrict__ hn = g_hb[t & 1];
        // zig-zag: odd steps walk K from the top -- L2 still holds that tail
        const int koff  = (t & 1) ? (H_ - 64) : 0;
        const int kstep = (t & 1) ? -64 : 64;
        const bf16_t* gpa = Abuf + aofsg + koff;
        const bf16_t* gpb = gb0 + koff;

        // B is immutable: stage chunks 0,1 BEFORE the dependency wait.
        ISSUE_B(0); ISSUE_B(1);                       // 4 ops

        // wait until all 16 writers of rows [mtile*64,+64) finished t-1
        if (tid == 0) {
            while (__hip_atomic_load(&g_cnt[(t - 1) * 16 + mtile],
                                     __ATOMIC_RELAXED,
                                     __HIP_MEMORY_SCOPE_AGENT) != 16)
                __builtin_amdgcn_s_sleep(2);
        }
        // raw barrier: keeps the B prefetch alive (no vmcnt(0) drain);
        // sc0 A-loads read the fresh XCD L2 (v7-proven pattern).
        asm volatile("s_barrier" ::: "memory");

        // prologue: queue = B0,B1 | A0,A1,B2,B3,A2,A3 (12 ops); first
        // vmcnt(6) retires B0,B1,A0,A1 -> chunks 0,1 ready; leaves 2,3.
        ISSUE_A(0); ISSUE_A(1); ISSUE_B(2); ISSUE_B(3);
        ISSUE_A(2); ISSUE_A(3);

#pragma unroll
        for (int i = 0; i < 4; ++i)
#pragma unroll
            for (int j = 0; j < 4; ++j) acc[i][j] = (f32x4)(0.f);

        // 16 super-iters, 6-slot ring, 2 chunk-pairs in flight, vmcnt(6).
        ITR(0, 6);  ITR(1, 6);  ITR(2, 6);  ITR(3, 6);
        ITR(4, 6);  ITR(5, 6);  ITR(6, 6);  ITR(7, 6);
        ITR(8, 6);  ITR(9, 6);  ITR(10, 6); ITR(11, 6);
        ITR(12, 6); ITR(13, 6);               // u13 stages chunks 30,31
        wait_vm_barrier<6>();                 // u14: chunks 28,29
        if (kh == 0) COMPUTE(4) else if (kh == 1) COMPUTE(5)
        wait_vm_barrier<0>();                 // u15: chunks 30,31
        if (kh == 2) COMPUTE(0) else if (kh == 3) COMPUTE(1)

        // ring slots still being read by u15's computing waves -> barrier
        // before the reduce scratch (aliases slots 0,1 among others).
        __syncthreads();

        // ---- 4-way K-quarter reduce, conflict-free b128 fragment layout.
        // Writer (nh,kh) writes its 3 non-kept i-blocks into slot
        // w2 = kh - (kh > i); reader i==kh just sums slots 0..2.
#pragma unroll
        for (int i = 0; i < 4; ++i)
            if (i != kh) {
                const int w2 = kh - (kh > i ? 1 : 0);
#pragma unroll
                for (int j = 0; j < 4; ++j)
                    *(f32x4*)&red[RIDX(i, w2, j)] = acc[i][j];
            }
        __syncthreads();

        // finish own i-block (= kh): sum 3 partials, then epilogue.
#define FIN(K)                                                              \
        {                                                                   \
            _Pragma("unroll")                                               \
            for (int w2 = 0; w2 < 3; ++w2)                                  \
                _Pragma("unroll")                                           \
                for (int j = 0; j < 4; ++j)                                 \
                    acc[K][j] += *(const f32x4*)&red[RIDX(K, w2, j)];       \
            const int row0 = mtile * 64 + (K) * 16 + fq * 4;                \
            float xv[4];                                                    \
            _Pragma("unroll")                                               \
            for (int r = 0; r < 4; ++r) xv[r] = x[(row0 + r) * T_ + t];     \
            _Pragma("unroll")                                               \
            for (int j = 0; j < 4; ++j) {                                   \
                const int col = bn * 128 + nh * 64 + j * 16 + fr;           \
                _Pragma("unroll")                                           \
                for (int r = 0; r < 4; ++r)                                 \
                    hn[(size_t)(row0 + r) * H_ + col] =                     \
                        (bf16_t)tanhf(acc[K][j][r] + xv[r] * wv[j] + bv[j]);\
            }                                                               \
        }
        if (kh == 0)      FIN(0)
        else if (kh == 1) FIN(1)
        else if (kh == 2) FIN(2)
        else              FIN(3)
#undef FIN

        // publish: drain this wave's stores to L2, join waves, bump counter.
        asm volatile("s_waitcnt vmcnt(0)" ::: "memory");
        __syncthreads();
        if (tid == 0)
            __hip_atomic_fetch_add(&g_cnt[t * 16 + mtile], 1, __ATOMIC_RELAXED,
                                   __HIP_MEMORY_SCOPE_AGENT);
    }
#undef RIDX
#undef ITR
#undef COMPUTE
#undef ISSUE_AB
#undef ISSUE_B
#undef ISSUE_A
}

// p = h_T @ W_ph + b_p : one wave per batch row, fp32 accumulate.
__global__ __launch_bounds__(64) void rnn_proj(const float* __restrict__ Wph,
                                               const float* __restrict__ bp,
                                               float* __restrict__ out, int sb) {
    const int b = blockIdx.x;
    const int l = threadIdx.x;
    const bf16_t* h = g_hb[sb] + (size_t)b * H_;
    float acc[C_];
#pragma unroll
    for (int c = 0; c < C_; ++c) acc[c] = 0.f;
    for (int k = l; k < H_; k += 64) {
        const float hv = (float)h[k];
#pragma unroll
        for (int c = 0; c < C_; ++c)
            acc[c] = fmaf(hv, Wph[k * C_ + c], acc[c]);
    }
#pragma unroll
    for (int off = 32; off > 0; off >>= 1)
#pragma unroll
        for (int c = 0; c < C_; ++c) acc[c] += __shfl_down(acc[c], off);
    if (l == 0) {
#pragma unroll
        for (int c = 0; c < C_; ++c) out[b * C_ + c] = acc[c] + bp[c];
    }
}

extern "C" void kernel_launch(void* const* d_in, const int* in_sizes, int n_in,
                              void* d_out, int out_size, void* d_ws, size_t ws_size,
                              hipStream_t stream) {
    const float* x   = (const float*)d_in[0];   // [1024,128]
    const float* Whx = (const float*)d_in[1];   // [1,2048]
    const float* Whh = (const float*)d_in[2];   // [2048,2048]
    const float* bh  = (const float*)d_in[3];   // [2048]
    const float* Wph = (const float*)d_in[4];   // [2048,10]
    const float* bp  = (const float*)d_in[5];   // [1,10]
    float* out = (float*)d_out;                 // [1024,10]

    static bool attr_set = false;
    if (!attr_set) {
        hipFuncSetAttribute((const void*)rnn_persist,
                            hipFuncAttributeMaxDynamicSharedMemorySize, 147456);
        attr_set = true;
    }

    prep_whhT<<<dim3(64, 64), 256, 0, stream>>>(Whh);
    rnn_init<<<(B_ * H_ / 4) / 256, 256, 0, stream>>>(x, Whx, bh);
    rnn_persist<<<256, 512, 147456, stream>>>(x, Whx, bh);
    rnn_proj<<<B_, 64, 0, stream>>>(Wph, bp, out, (T_ - 1) & 1);
}

// Round 11
// 2077.568 us; speedup vs baseline: 1.3275x; 1.0887x over previous
//
#include <hip/hip_runtime.h>
#include <math.h>

#define B_ 1024
#define T_ 128
#define H_ 2048
#define C_ 10

typedef __bf16 bf16_t;
typedef float f32x4 __attribute__((ext_vector_type(4)));

// fp8 scaling: A = h * 2^7, B = W_hh * 2^12; acc * 2^-19 in the epilogue.
#define SA_  128.0f
#define SB_  4096.0f
#define INV_ 1.9073486328125e-6f   // 2^-19

// Static device storage: fp8 h ping-pong (4 MB), fp8 W_hh^T (4 MB),
// bf16 h_T for the projection, per-(t,bm) readiness counters.
__device__ __align__(16) unsigned char g_h8[2][(size_t)B_ * H_];
__device__ __align__(16) unsigned char g_w8[(size_t)H_ * H_];
__device__ __align__(16) bf16_t g_hT[(size_t)B_ * H_];
__device__ int g_cnt[T_ * 8];   // [t][bm]; t=0 seeded to 32 by rnn_init

// AUX: cache policy. 0 = default; 1 = sc0 (force L1 miss -> read XCD L2).
template <int AUX>
__device__ __forceinline__ void gload16(const unsigned char* g, unsigned char* l) {
    __builtin_amdgcn_global_load_lds(
        (const __attribute__((address_space(1))) void*)g,
        (__attribute__((address_space(3))) void*)l, 16, 0, AUX);
}

// Counted-vmcnt barrier: retire oldest pipeline stage without draining.
template <int VM>
__device__ __forceinline__ void wait_vm_barrier() {
    asm volatile("s_waitcnt vmcnt(%0)\n\ts_barrier" :: "n"(VM) : "memory");
}

// One-time: g_w8[n][k] = fp8(W_hh[k][n] * SB_) — K-contiguous fp8 B operand.
__global__ __launch_bounds__(256) void prep_w8(const float* __restrict__ Whh) {
    __shared__ float tile[32][33];
    const int i  = threadIdx.x >> 3;
    const int j4 = (threadIdx.x & 7) * 4;
    const int r0 = blockIdx.y * 32;
    const int c0 = blockIdx.x * 32;
    f32x4 v = *(const f32x4*)(Whh + (size_t)(r0 + i) * H_ + c0 + j4);
    tile[i][j4 + 0] = v[0]; tile[i][j4 + 1] = v[1];
    tile[i][j4 + 2] = v[2]; tile[i][j4 + 3] = v[3];
    __syncthreads();
    float f[4];
#pragma unroll
    for (int r = 0; r < 4; ++r) f[r] = tile[j4 + r][i] * SB_;
    int u = __builtin_amdgcn_cvt_pk_fp8_f32(f[0], f[1], 0, false);
    u = __builtin_amdgcn_cvt_pk_fp8_f32(f[2], f[3], u, true);
    *(int*)&g_w8[(size_t)(c0 + i) * H_ + r0 + j4] = u;
}

// t = 0: h = tanh(x[:,0]*W_hx + b_h) -> fp8*SA_; also (re)init counters.
__global__ __launch_bounds__(256) void rnn_init(const float* __restrict__ x,
                                                const float* __restrict__ Whx,
                                                const float* __restrict__ bh) {
    if (blockIdx.x == 0) {
        for (int i = threadIdx.x; i < T_ * 8; i += 256)
            g_cnt[i] = (i < 8) ? 32 : 0;   // g_cnt[0][*] = 32 (h0 ready)
    }
    const int gid = blockIdx.x * 256 + threadIdx.x;
    const int row = gid >> 9;
    const int col = (gid & 511) << 2;
    const float xv = x[(size_t)row * T_];
    f32x4 w = *(const f32x4*)&Whx[col];
    f32x4 b = *(const f32x4*)&bh[col];
    float th[4];
#pragma unroll
    for (int j = 0; j < 4; ++j) th[j] = tanhf(fmaf(xv, w[j], b[j])) * SA_;
    int u = __builtin_amdgcn_cvt_pk_fp8_f32(th[0], th[1], 0, false);
    u = __builtin_amdgcn_cvt_pk_fp8_f32(th[2], th[3], u, true);
    *(int*)&g_h8[0][(size_t)row * H_ + col] = u;
}

// Persistent RNN. v11 = v7's proven skeleton (8 waves 2Mx2Nx2K-parity,
// 6-slot ring, counted vmcnt, XCD-local rendezvous, zig-zag, sc0-A) with
// BOTH operands staged in fp8 e4m3 via mfma_f32_16x16x32_fp8_fp8:
// staged bytes per CU per step halve, 768 -> 384 KB. Rationale: staging
// delivery is the measured invariant across v1/v7/v10 (~43 GB/s/CU), so
// step time ~ staged_bytes / 43 GB/s. fp8 error enters only the
// recurrence term (~2% of h); the x*W_hx + b_h + tanh path stays f32 and
// h is re-quantized fresh each step; h_T stored bf16 for the projection.
// Per pair (2 chunks): 3 loads/thread {A-even, A-odd, B}; steady vmcnt(3).
// LDS: A 6x8KB + B 6x4KB = 72 KB; reduce scratch aliases A slots 2..5.
// ds_read_b64 frags with 16B-granule XOR swizzle (unit ^ (row&3)).
__global__ __launch_bounds__(512, 1) void rnn_persist(const float* __restrict__ x,
                                                      const float* __restrict__ Whx,
                                                      const float* __restrict__ bh) {
    extern __shared__ __align__(16) unsigned char smem[];
    unsigned char* As = smem;            // 6 slots x 8192 B
    unsigned char* Bs = smem + 49152;    // 6 slots x 4096 B
    float* red = (float*)(smem + 16384); // 32 KB; aliases A slots 2..5 only

    const int tid  = threadIdx.x;
    const int lane = tid & 63;
    const int wave = tid >> 6;                       // 0..7
    const int li  = blockIdx.x;
    const int bm  = li & 7;                          // == XCD (blk%8 map)
    const int bn  = li >> 3;                         // 0..31

    const int wm = (wave & 1) * 64;                  // M band (64 rows)
    const int wn = ((wave >> 1) & 1) * 32;           // N band (32 cols)
    const int kh = wave >> 2;                        // K parity within pair
    const int fr = lane & 15, fq = lane >> 4;

    // A staging: chunk = 128 rows x 64 B; thread -> row tid>>2, 16B-unit
    // tid&3, global unit = (tid&3)^(row&3) (XOR swizzle, DMA-compatible).
    const int rA  = tid >> 2;                        // 0..127
    const int cgA = (tid & 3) ^ (rA & 3);
    const size_t aofsg = (size_t)(bm * 128 + rA) * H_ + cgA * 16;
    // B staging: chunk = 64 rows x 64 B; 256 threads; tid>>8 picks which
    // chunk of the pair this thread stages (uniform 1 B-load per pair).
    const int bidx = tid & 255;
    const int rB   = bidx >> 2;
    const int cgB  = (bidx & 3) ^ (rB & 3);
    const int pT   = tid >> 8;                       // 0: first, 1: second
    const unsigned char* const gb0 =
        g_w8 + (size_t)(bn * 64 + rB) * H_ + cgB * 16;

#define SLP(P) ((2 * (P)) % 6)   /* even: pair P's first slot */

    // Issue pair P: A first-chunk -> slot SLP, A second -> SLP+1, B -> SLP+pT.
#define ISSUE_PAIR(P)                                                       \
    do {                                                                    \
        gload16<1>(gpa,         As + SLP(P) * 8192 + tid * 16);             \
        gload16<1>(gpa + kstep, As + (SLP(P) + 1) * 8192 + tid * 16);       \
        gload16<0>(gpb,         Bs + (SLP(P) + pT) * 4096 + bidx * 16);     \
        gpa += kstep2; gpb += kstep2;                                       \
    } while (0)

    // frag byte offsets: row*64 + (((cc*4+fq)>>1) ^ (row&3))*16 + (fq&1)*8
    const int xt0 = ((fq >> 1) ^ (fr & 3)) * 16 + (fq & 1) * 8;        // cc=0
    const int xt1 = (((2 + (fq >> 1)) & 3) ^ (fr & 3)) * 16 + (fq & 1) * 8;
    int aoff[4][2], boff[2][2];
#pragma unroll
    for (int i = 0; i < 4; ++i) {
        aoff[i][0] = (wm + i * 16 + fr) * 64 + xt0;
        aoff[i][1] = (wm + i * 16 + fr) * 64 + xt1;
    }
#pragma unroll
    for (int j = 0; j < 2; ++j) {
        boff[j][0] = (wn + j * 16 + fr) * 64 + xt0;
        boff[j][1] = (wn + j * 16 + fr) * 64 + xt1;
    }

    f32x4 acc[4][2];

    // One chunk: 8 A-b64 + 4 B-b64 reads, 16 fp8 MFMA.
#define COMPUTE(S)                                                          \
    {                                                                       \
        _Pragma("unroll")                                                   \
        for (int cc = 0; cc < 2; ++cc) {                                    \
            long af[4], bfv[2];                                             \
            _Pragma("unroll")                                               \
            for (int j = 0; j < 2; ++j)                                     \
                bfv[j] = *(const long*)(Bs + (S) * 4096 + boff[j][cc]);     \
            _Pragma("unroll")                                               \
            for (int i = 0; i < 4; ++i)                                     \
                af[i] = *(const long*)(As + (S) * 8192 + aoff[i][cc]);      \
            _Pragma("unroll")                                               \
            for (int i = 0; i < 4; ++i)                                     \
                _Pragma("unroll")                                           \
                for (int j = 0; j < 2; ++j)                                 \
                    acc[i][j] = __builtin_amdgcn_mfma_f32_16x16x32_fp8_fp8( \
                        af[i], bfv[j], acc[i][j], 0, 0, 0);                 \
        }                                                                   \
    }

    // Epoch U: retire pair U (counted), stage pair U+2, compute own chunk.
#define EPOCH(U, V)                                                         \
    do {                                                                    \
        wait_vm_barrier<V>();                                               \
        ISSUE_PAIR((U) + 2);                                                \
        if (kh == 0) COMPUTE(SLP(U)) else COMPUTE(SLP(U) + 1)               \
    } while (0)

    // epilogue constants (step-invariant)
    float wv[2], bv[2];
#pragma unroll
    for (int j = 0; j < 2; ++j) {
        const int col = bn * 64 + wn + j * 16 + fr;
        wv[j] = Whx[col];
        bv[j] = bh[col];
    }

#pragma unroll 1
    for (int t = 1; t < T_; ++t) {
        const unsigned char* __restrict__ Abuf = g_h8[(t - 1) & 1];
        unsigned char* __restrict__ hn = g_h8[t & 1];
        // zig-zag: odd steps walk K from the top -- L2 still holds that tail
        const int koff   = (t & 1) ? (H_ - 64) : 0;      // bytes (1B/elem)
        const int kstep  = (t & 1) ? -64 : 64;
        const int kstep2 = 2 * kstep;
        const unsigned char* gpa = Abuf + aofsg + koff;
        const unsigned char* gpb = gb0 + koff + pT * kstep;

        // B is immutable: stage pairs 0,1 BEFORE the dependency wait.
        gload16<0>(gpb, Bs + (0 + pT) * 4096 + bidx * 16); gpb += kstep2;
        gload16<0>(gpb, Bs + (2 + pT) * 4096 + bidx * 16); gpb += kstep2;

        // wait until all 32 same-XCD writers of h-rows bm finished step t-1
        if (tid == 0) {
            while (__hip_atomic_load(&g_cnt[(t - 1) * 8 + bm], __ATOMIC_RELAXED,
                                     __HIP_MEMORY_SCOPE_AGENT) != 32)
                __builtin_amdgcn_s_sleep(2);
        }
        // raw barrier: keeps the B prefetch alive (no vmcnt(0) drain);
        // sc0 A-loads read the fresh XCD L2 (v7-proven pattern).
        asm volatile("s_barrier" ::: "memory");

        // A pairs 0,1. Queue/thread: [B0,B1,A0e,A0o,A1e,A1o].
        gload16<1>(gpa,         As + 0 * 8192 + tid * 16);
        gload16<1>(gpa + kstep, As + 1 * 8192 + tid * 16);
        gpa += kstep2;
        gload16<1>(gpa,         As + 2 * 8192 + tid * 16);
        gload16<1>(gpa + kstep, As + 3 * 8192 + tid * 16);
        gpa += kstep2;

#pragma unroll
        for (int i = 0; i < 4; ++i)
#pragma unroll
            for (int j = 0; j < 2; ++j) acc[i][j] = (f32x4)(0.f);

        // 16 pair-epochs, 6 chunk-slots, 2 pairs in flight.
        // E0 vmcnt(2) retires B0,B1,A0e,A0o; steady vmcnt(3) = one {A,A,B}.
        EPOCH(0, 2);  EPOCH(1, 3);  EPOCH(2, 3);  EPOCH(3, 3);
        EPOCH(4, 3);  EPOCH(5, 3);  EPOCH(6, 3);  EPOCH(7, 3);
        EPOCH(8, 3);  EPOCH(9, 3);  EPOCH(10, 3); EPOCH(11, 3);
        EPOCH(12, 3); EPOCH(13, 3);                // E13 stages pair 15
        wait_vm_barrier<3>();                      // E14 (SLP(14)=4)
        if (kh == 0) COMPUTE(4) else COMPUTE(5)
        wait_vm_barrier<0>();                      // E15 (SLP(15)=0)
        if (kh == 0) COMPUTE(0) else COMPUTE(1)

        // ---- cross-wave K-parity reduce (partner = wave^4), raw fragment
        // layout (f32x4/lane, b128, conflict-free). red aliases A slots
        // 2..5 (dead); E15 computes slots 0,1 only -> disjoint.
        {
            float* wr = red + wave * 1024;
            if (kh == 0) {
                *(f32x4*)&wr[0 * 256 + lane * 4] = acc[2][0];
                *(f32x4*)&wr[1 * 256 + lane * 4] = acc[2][1];
                *(f32x4*)&wr[2 * 256 + lane * 4] = acc[3][0];
                *(f32x4*)&wr[3 * 256 + lane * 4] = acc[3][1];
            } else {
                *(f32x4*)&wr[0 * 256 + lane * 4] = acc[0][0];
                *(f32x4*)&wr[1 * 256 + lane * 4] = acc[0][1];
                *(f32x4*)&wr[2 * 256 + lane * 4] = acc[1][0];
                *(f32x4*)&wr[3 * 256 + lane * 4] = acc[1][1];
            }
        }
        __syncthreads();
        {
            const float* rd = red + (wave ^ 4) * 1024;
            if (kh == 0) {
                acc[0][0] += *(const f32x4*)&rd[0 * 256 + lane * 4];
                acc[0][1] += *(const f32x4*)&rd[1 * 256 + lane * 4];
                acc[1][0] += *(const f32x4*)&rd[2 * 256 + lane * 4];
                acc[1][1] += *(const f32x4*)&rd[3 * 256 + lane * 4];
            } else {
                acc[2][0] += *(const f32x4*)&rd[0 * 256 + lane * 4];
                acc[2][1] += *(const f32x4*)&rd[1 * 256 + lane * 4];
                acc[3][0] += *(const f32x4*)&rd[2 * 256 + lane * 4];
                acc[3][1] += *(const f32x4*)&rd[3 * 256 + lane * 4];
            }
        }

        // epilogue: f32 (acc*2^-19 + x_t*W_hx + b_h), tanh, fp8*SA_ store;
        // last step additionally stores bf16 h_T for the projection.
#define EPI(I)                                                              \
        {                                                                   \
            const int row0 = bm * 128 + wm + (I) * 16 + fq * 4;             \
            float xv[4];                                                    \
            _Pragma("unroll")                                               \
            for (int r = 0; r < 4; ++r) xv[r] = x[(row0 + r) * T_ + t];     \
            _Pragma("unroll")                                               \
            for (int j = 0; j < 2; ++j) {                                   \
                const int col = bn * 64 + wn + j * 16 + fr;                 \
                _Pragma("unroll")                                           \
                for (int r = 0; r < 4; ++r) {                               \
                    const float hv = tanhf(fmaf(acc[I][j][r], INV_,         \
                                           fmaf(xv[r], wv[j], bv[j])));     \
                    const int q8 = __builtin_amdgcn_cvt_pk_fp8_f32(         \
                        hv * SA_, 0.f, 0, false);                           \
                    hn[(size_t)(row0 + r) * H_ + col] =                     \
                        (unsigned char)(q8 & 0xff);                         \
                    if (t == T_ - 1)                                        \
                        g_hT[(size_t)(row0 + r) * H_ + col] = (bf16_t)hv;   \
                }                                                           \
            }                                                               \
        }
        if (kh == 0) { EPI(0) EPI(1) } else { EPI(2) EPI(3) }
#undef EPI

        // publish: drain this wave's stores to L2, join waves, bump counter.
        asm volatile("s_waitcnt vmcnt(0)" ::: "memory");
        __syncthreads();
        if (tid == 0)
            __hip_atomic_fetch_add(&g_cnt[t * 8 + bm], 1, __ATOMIC_RELAXED,
                                   __HIP_MEMORY_SCOPE_AGENT);
    }
#undef EPOCH
#undef COMPUTE
#undef ISSUE_PAIR
#undef SLP
}

// p = h_T @ W_ph + b_p : one wave per batch row, fp32 accumulate.
__global__ __launch_bounds__(64) void rnn_proj(const float* __restrict__ Wph,
                                               const float* __restrict__ bp,
                                               float* __restrict__ out) {
    const int b = blockIdx.x;
    const int l = threadIdx.x;
    const bf16_t* h = g_hT + (size_t)b * H_;
    float acc[C_];
#pragma unroll
    for (int c = 0; c < C_; ++c) acc[c] = 0.f;
    for (int k = l; k < H_; k += 64) {
        const float hv = (float)h[k];
#pragma unroll
        for (int c = 0; c < C_; ++c)
            acc[c] = fmaf(hv, Wph[k * C_ + c], acc[c]);
    }
#pragma unroll
    for (int off = 32; off > 0; off >>= 1)
#pragma unroll
        for (int c = 0; c < C_; ++c) acc[c] += __shfl_down(acc[c], off);
    if (l == 0) {
#pragma unroll
        for (int c = 0; c < C_; ++c) out[b * C_ + c] = acc[c] + bp[c];
    }
}

extern "C" void kernel_launch(void* const* d_in, const int* in_sizes, int n_in,
                              void* d_out, int out_size, void* d_ws, size_t ws_size,
                              hipStream_t stream) {
    const float* x   = (const float*)d_in[0];   // [1024,128]
    const float* Whx = (const float*)d_in[1];   // [1,2048]
    const float* Whh = (const float*)d_in[2];   // [2048,2048]
    const float* bh  = (const float*)d_in[3];   // [2048]
    const float* Wph = (const float*)d_in[4];   // [2048,10]
    const float* bp  = (const float*)d_in[5];   // [1,10]
    float* out = (float*)d_out;                 // [1024,10]

    static bool attr_set = false;
    if (!attr_set) {
        hipFuncSetAttribute((const void*)rnn_persist,
                            hipFuncAttributeMaxDynamicSharedMemorySize, 73728);
        attr_set = true;
    }

    prep_w8<<<dim3(64, 64), 256, 0, stream>>>(Whh);
    rnn_init<<<(B_ * H_ / 4) / 256, 256, 0, stream>>>(x, Whx, bh);
    rnn_persist<<<256, 512, 73728, stream>>>(x, Whx, bh);
    rnn_proj<<<B_, 64, 0, stream>>>(Wph, bp, out);
}

// Round 12
// 1453.817 us; speedup vs baseline: 1.8970x; 1.4290x over previous
//
#include <hip/hip_runtime.h>
#include <math.h>

#define B_ 1024
#define T_ 128
#define H_ 2048
#define C_ 10

typedef __bf16 bf16_t;
typedef float f32x4 __attribute__((ext_vector_type(4)));
typedef long  lx2  __attribute__((ext_vector_type(2)));

// fp8 scaling: A = h * 2^7, B = W_hh * 2^12; acc * 2^-19 in the epilogue.
#define SA_  128.0f
#define SB_  4096.0f
#define INV_ 1.9073486328125e-6f   // 2^-19

// Static device storage: fp8 h ping-pong (2x2 MB), fp8 W_hh^T (4 MB),
// bf16 h_T for the projection, per-(t,bm) readiness counters.
// fp8 layouts use frag-pair interleaving per 128B superchunk: unit j=p*4+f
// (16B) = K32-block (2p)'s f-th 8B || block (2p+1)'s f-th 8B, so one
// ds_read_b128 yields both fragments of a cc-pair. perm(k):
//   b=(k>>5)&3, f=(k>>3)&3, e=k&7 -> (k&~127) + (b>>1)*64 + f*16 + (b&1)*8 + e
__device__ __align__(16) unsigned char g_h8[2][(size_t)B_ * H_];
__device__ __align__(16) unsigned char g_w8[(size_t)H_ * H_];
__device__ __align__(16) bf16_t g_hT[(size_t)B_ * H_];
__device__ int g_cnt[T_ * 8];   // [t][bm]; t=0 seeded to 32 by rnn_init

__device__ __forceinline__ int permk(int k) {
    const int b = (k >> 5) & 3, f = (k >> 3) & 3, e = k & 7;
    return (k & ~127) + ((b >> 1) << 6) + (f << 4) + ((b & 1) << 3) + e;
}

// AUX: cache policy. 0 = default; 1 = sc0 (force L1 miss -> read XCD L2).
template <int AUX>
__device__ __forceinline__ void gload16(const unsigned char* g, unsigned char* l) {
    __builtin_amdgcn_global_load_lds(
        (const __attribute__((address_space(1))) void*)g,
        (__attribute__((address_space(3))) void*)l, 16, 0, AUX);
}

// Counted-vmcnt barrier: retire oldest pipeline stage without draining.
template <int VM>
__device__ __forceinline__ void wait_vm_barrier() {
    asm volatile("s_waitcnt vmcnt(%0)\n\ts_barrier" :: "n"(VM) : "memory");
}

// One-time: g_w8[n][perm(k)] = fp8(W_hh[k][n] * SB_).
__global__ __launch_bounds__(256) void prep_w8(const float* __restrict__ Whh) {
    __shared__ float tile[32][33];
    const int i  = threadIdx.x >> 3;
    const int j4 = (threadIdx.x & 7) * 4;
    const int r0 = blockIdx.y * 32;
    const int c0 = blockIdx.x * 32;
    f32x4 v = *(const f32x4*)(Whh + (size_t)(r0 + i) * H_ + c0 + j4);
    tile[i][j4 + 0] = v[0]; tile[i][j4 + 1] = v[1];
    tile[i][j4 + 2] = v[2]; tile[i][j4 + 3] = v[3];
    __syncthreads();
    float f[4];
#pragma unroll
    for (int r = 0; r < 4; ++r) f[r] = tile[j4 + r][i] * SB_;
    int u = __builtin_amdgcn_cvt_pk_fp8_f32(f[0], f[1], 0, false);
    u = __builtin_amdgcn_cvt_pk_fp8_f32(f[2], f[3], u, true);
    // k = r0+j4 .. +3 contiguous (k%8 in {0,4}) -> contiguous after perm
    *(int*)&g_w8[(size_t)(c0 + i) * H_ + permk(r0 + j4)] = u;
}

// t = 0: h = tanh(x[:,0]*W_hx + b_h) -> fp8*SA_ (permuted); init counters.
__global__ __launch_bounds__(256) void rnn_init(const float* __restrict__ x,
                                                const float* __restrict__ Whx,
                                                const float* __restrict__ bh) {
    if (blockIdx.x == 0) {
        for (int i = threadIdx.x; i < T_ * 8; i += 256)
            g_cnt[i] = (i < 8) ? 32 : 0;   // g_cnt[0][*] = 32 (h0 ready)
    }
    const int gid = blockIdx.x * 256 + threadIdx.x;
    const int row = gid >> 9;
    const int col = (gid & 511) << 2;
    const float xv = x[(size_t)row * T_];
    f32x4 w = *(const f32x4*)&Whx[col];
    f32x4 b = *(const f32x4*)&bh[col];
    float th[4];
#pragma unroll
    for (int j = 0; j < 4; ++j) th[j] = tanhf(fmaf(xv, w[j], b[j])) * SA_;
    int u = __builtin_amdgcn_cvt_pk_fp8_f32(th[0], th[1], 0, false);
    u = __builtin_amdgcn_cvt_pk_fp8_f32(th[2], th[3], u, true);
    *(int*)&g_h8[0][(size_t)row * H_ + permk(col)] = u;
}

// Persistent RNN. v12 = v11's fp8 staging economy (384 KB/CU/step) with the
// PROVEN conflict-free LDS geometry (v1-v10: 128B rows, 8x16B units, XOR
// (row&7), b128 reads -- measured 0 conflicts; v11's 64B-row b64 variant
// cost 5.7e8 conflict cycles and ate the fp8 win). K-tile = 128 fp8 =
// 128B rows via frag-pair-interleaved global layout (one b128 read = both
// fragments of a cc-pair). Skeleton = v7 verbatim: 8 waves 2Mx2Nx2K-parity,
// 6-slot ring (A 16KB + B 8KB = 144 KB), 2 K128-chunks per epoch, 8
// epochs, steady vmcnt(6) (ledger 4,6,6,6,6,6|6,0), pre-rendezvous B
// prefetch, sc0-A, zig-zag, f32x4 reduce aliased into dead slots 4,5.
__global__ __launch_bounds__(512, 1) void rnn_persist(const float* __restrict__ x,
                                                      const float* __restrict__ Whx,
                                                      const float* __restrict__ bh) {
    extern __shared__ __align__(16) unsigned char smem[];
    unsigned char* As = smem;             // 6 slots x 16384 B (128r x 128B)
    unsigned char* Bs = smem + 98304;     // 6 slots x 8192 B  (64r x 128B)
    float* red = (float*)(As + 4 * 16384);  // 32 KB; aliases A slots 4,5

    const int tid  = threadIdx.x;
    const int lane = tid & 63;
    const int wave = tid >> 6;                       // 0..7
    const int li  = blockIdx.x;
    const int bm  = li & 7;                          // == XCD (blk%8 map)
    const int bn  = li >> 3;                         // 0..31

    const int wm = (wave & 1) * 64;                  // M band (64 rows)
    const int wn = ((wave >> 1) & 1) * 32;           // N band (32 cols)
    const int kh = wave >> 2;                        // chunk parity
    const int fr = lane & 15, fq = lane >> 4;

    // Staging (v1-proven): thread t -> row t>>3, lds-unit t&7; global unit
    // = (t&7)^(row&7) (pre-swizzled source; DMA dest linear).
    const int rA = tid >> 3;                         // 0..63
    const int cg = (tid & 7) ^ (rA & 7);
    const size_t aofsg = (size_t)(bm * 128 + rA) * H_ + cg * 16;
    const unsigned char* const gb0 =
        g_w8 + (size_t)(bn * 64 + rA) * H_ + cg * 16;

    // A chunk = 128 rows x 128B: 2 loads/thread. B chunk = 64 x 128B: 1.
#define ISSUE_A(S)                                                       \
    do {                                                                 \
        gload16<1>(gpa,              As + (S) * 16384 + tid * 16);       \
        gload16<1>(gpa + 64 * H_,    As + (S) * 16384 + (tid + 512) * 16);\
        gpa += kstep;                                                    \
    } while (0)
#define ISSUE_B(S)                                                       \
    do {                                                                 \
        gload16<0>(gpb, Bs + (S) * 8192 + tid * 16);                     \
        gpb += kstep;                                                    \
    } while (0)

    // frag read offsets (bytes): row*128 + ((p*4+fq) ^ (row&7))*16;
    // row&7 == fr&7. One b128 = cc-pair (2p, 2p+1) fragments.
    const int xr0 = ((0 + fq) ^ (fr & 7)) * 16;
    const int xr1 = ((4 + fq) ^ (fr & 7)) * 16;
    int aoff[4][2], boff[2][2];
#pragma unroll
    for (int i = 0; i < 4; ++i) {
        aoff[i][0] = (wm + i * 16 + fr) * 128 + xr0;
        aoff[i][1] = (wm + i * 16 + fr) * 128 + xr1;
    }
#pragma unroll
    for (int j = 0; j < 2; ++j) {
        boff[j][0] = (wn + j * 16 + fr) * 128 + xr0;
        boff[j][1] = (wn + j * 16 + fr) * 128 + xr1;
    }

    f32x4 acc[4][2];

    // One K128 chunk: 12 ds_read_b128 + 32 fp8 MFMA.
#define COMPUTE(S)                                                          \
    {                                                                       \
        _Pragma("unroll")                                                   \
        for (int p = 0; p < 2; ++p) {                                       \
            lx2 af[4], bfv[2];                                              \
            _Pragma("unroll")                                               \
            for (int j = 0; j < 2; ++j)                                     \
                bfv[j] = *(const lx2*)(Bs + (S) * 8192 + boff[j][p]);       \
            _Pragma("unroll")                                               \
            for (int i = 0; i < 4; ++i)                                     \
                af[i] = *(const lx2*)(As + (S) * 16384 + aoff[i][p]);       \
            _Pragma("unroll")                                               \
            for (int i = 0; i < 4; ++i)                                     \
                _Pragma("unroll")                                           \
                for (int j = 0; j < 2; ++j) {                               \
                    acc[i][j] = __builtin_amdgcn_mfma_f32_16x16x32_fp8_fp8( \
                        af[i][0], bfv[j][0], acc[i][j], 0, 0, 0);           \
                    acc[i][j] = __builtin_amdgcn_mfma_f32_16x16x32_fp8_fp8( \
                        af[i][1], bfv[j][1], acc[i][j], 0, 0, 0);           \
                }                                                           \
        }                                                                   \
    }

    // Epoch U: retire chunks 2U,2U+1 (counted), stage 2U+4,2U+5, compute
    // own-parity chunk (kh0 -> even slot, kh1 -> odd). All waves busy.
#define EPOCH(U, V)                                                         \
    do {                                                                    \
        wait_vm_barrier<V>();                                               \
        ISSUE_A((2 * (U) + 4) % 6); ISSUE_B((2 * (U) + 4) % 6);             \
        ISSUE_A((2 * (U) + 5) % 6); ISSUE_B((2 * (U) + 5) % 6);             \
        if (kh == 0) COMPUTE((2 * (U)) % 6)                                 \
        else         COMPUTE((2 * (U) + 1) % 6)                             \
    } while (0)

    // epilogue constants (step-invariant)
    float wv[2], bv[2];
    int pcol[2];
#pragma unroll
    for (int j = 0; j < 2; ++j) {
        const int col = bn * 64 + wn + j * 16 + fr;
        wv[j] = Whx[col];
        bv[j] = bh[col];
        pcol[j] = permk(col);
    }

#pragma unroll 1
    for (int t = 1; t < T_; ++t) {
        const unsigned char* __restrict__ Abuf = g_h8[(t - 1) & 1];
        unsigned char* __restrict__ hn = g_h8[t & 1];
        // zig-zag: odd steps walk K from the top -- L2 still holds that tail
        const int koff  = (t & 1) ? (H_ - 128) : 0;      // bytes
        const int kstep = (t & 1) ? -128 : 128;
        const unsigned char* gpa = Abuf + aofsg + koff;
        const unsigned char* gpb = gb0 + koff;

        // B is immutable: stage chunks 0..3 BEFORE the dependency wait.
        ISSUE_B(0); ISSUE_B(1); ISSUE_B(2); ISSUE_B(3);

        // wait until all 32 same-XCD writers of h-rows bm finished step t-1
        if (tid == 0) {
            while (__hip_atomic_load(&g_cnt[(t - 1) * 8 + bm], __ATOMIC_RELAXED,
                                     __HIP_MEMORY_SCOPE_AGENT) != 32)
                __builtin_amdgcn_s_sleep(2);
        }
        // raw barrier: keeps the B prefetch alive (no vmcnt(0) drain);
        // sc0 A-loads read the fresh XCD L2 (v7-proven pattern).
        asm volatile("s_barrier" ::: "memory");

        ISSUE_A(0); ISSUE_A(1); ISSUE_A(2); ISSUE_A(3);

#pragma unroll
        for (int i = 0; i < 4; ++i)
#pragma unroll
            for (int j = 0; j < 2; ++j) acc[i][j] = (f32x4)(0.f);

        // 8 epochs, 16 K128 chunks, 6-slot ring, 2 epochs in flight.
        // Queue at E0: [B0..B3, A0a,A0b..A3a,A3b] (12); vmcnt(4) retires
        // chunks 0,1; steady vmcnt(6) retires one epoch's 6 loads.
        EPOCH(0, 4); EPOCH(1, 6); EPOCH(2, 6);
        EPOCH(3, 6); EPOCH(4, 6); EPOCH(5, 6);   // E5 stages chunks 14,15
        wait_vm_barrier<6>();                    // E6: chunks 12,13
        if (kh == 0) COMPUTE(0) else COMPUTE(1)
        wait_vm_barrier<0>();                    // E7: chunks 14,15
        if (kh == 0) COMPUTE(2) else COMPUTE(3)

        // ---- cross-wave K-parity reduce (partner = wave^4), raw fragment
        // layout (f32x4/lane, b128, conflict-free). red aliases A slots
        // 4,5 (dead since E5); E7 computes slots 2,3 only -> disjoint.
        {
            float* wr = red + wave * 1024;
            if (kh == 0) {
                *(f32x4*)&wr[0 * 256 + lane * 4] = acc[2][0];
                *(f32x4*)&wr[1 * 256 + lane * 4] = acc[2][1];
                *(f32x4*)&wr[2 * 256 + lane * 4] = acc[3][0];
                *(f32x4*)&wr[3 * 256 + lane * 4] = acc[3][1];
            } else {
                *(f32x4*)&wr[0 * 256 + lane * 4] = acc[0][0];
                *(f32x4*)&wr[1 * 256 + lane * 4] = acc[0][1];
                *(f32x4*)&wr[2 * 256 + lane * 4] = acc[1][0];
                *(f32x4*)&wr[3 * 256 + lane * 4] = acc[1][1];
            }
        }
        __syncthreads();
        {
            const float* rd = red + (wave ^ 4) * 1024;
            if (kh == 0) {
                acc[0][0] += *(const f32x4*)&rd[0 * 256 + lane * 4];
                acc[0][1] += *(const f32x4*)&rd[1 * 256 + lane * 4];
                acc[1][0] += *(const f32x4*)&rd[2 * 256 + lane * 4];
                acc[1][1] += *(const f32x4*)&rd[3 * 256 + lane * 4];
            } else {
                acc[2][0] += *(const f32x4*)&rd[0 * 256 + lane * 4];
                acc[2][1] += *(const f32x4*)&rd[1 * 256 + lane * 4];
                acc[3][0] += *(const f32x4*)&rd[2 * 256 + lane * 4];
                acc[3][1] += *(const f32x4*)&rd[3 * 256 + lane * 4];
            }
        }

        // epilogue: f32 (acc*2^-19 + x_t*W_hx + b_h), tanh, fp8*SA_ store
        // at the permuted column; last step also stores bf16 h_T.
#define EPI(I)                                                              \
        {                                                                   \
            const int row0 = bm * 128 + wm + (I) * 16 + fq * 4;             \
            float xv[4];                                                    \
            _Pragma("unroll")                                               \
            for (int r = 0; r < 4; ++r) xv[r] = x[(row0 + r) * T_ + t];     \
            _Pragma("unroll")                                               \
            for (int j = 0; j < 2; ++j) {                                   \
                _Pragma("unroll")                                           \
                for (int r = 0; r < 4; ++r) {                               \
                    const float hv = tanhf(fmaf(acc[I][j][r], INV_,         \
                                           fmaf(xv[r], wv[j], bv[j])));     \
                    const int q8 = __builtin_amdgcn_cvt_pk_fp8_f32(         \
                        hv * SA_, 0.f, 0, false);                           \
                    hn[(size_t)(row0 + r) * H_ + pcol[j]] =                 \
                        (unsigned char)(q8 & 0xff);                         \
                    if (t == T_ - 1)                                        \
                        g_hT[(size_t)(row0 + r) * H_ +                      \
                             (bn * 64 + wn + j * 16 + fr)] = (bf16_t)hv;    \
                }                                                           \
            }                                                               \
        }
        if (kh == 0) { EPI(0) EPI(1) } else { EPI(2) EPI(3) }
#undef EPI

        // publish: drain this wave's stores to L2, join waves, bump counter.
        asm volatile("s_waitcnt vmcnt(0)" ::: "memory");
        __syncthreads();
        if (tid == 0)
            __hip_atomic_fetch_add(&g_cnt[t * 8 + bm], 1, __ATOMIC_RELAXED,
                                   __HIP_MEMORY_SCOPE_AGENT);
    }
#undef EPOCH
#undef COMPUTE
#undef ISSUE_B
#undef ISSUE_A
}

// p = h_T @ W_ph + b_p : one wave per batch row, fp32 accumulate.
__global__ __launch_bounds__(64) void rnn_proj(const float* __restrict__ Wph,
                                               const float* __restrict__ bp,
                                               float* __restrict__ out) {
    const int b = blockIdx.x;
    const int l = threadIdx.x;
    const bf16_t* h = g_hT + (size_t)b * H_;
    float acc[C_];
#pragma unroll
    for (int c = 0; c < C_; ++c) acc[c] = 0.f;
    for (int k = l; k < H_; k += 64) {
        const float hv = (float)h[k];
#pragma unroll
        for (int c = 0; c < C_; ++c)
            acc[c] = fmaf(hv, Wph[k * C_ + c], acc[c]);
    }
#pragma unroll
    for (int off = 32; off > 0; off >>= 1)
#pragma unroll
        for (int c = 0; c < C_; ++c) acc[c] += __shfl_down(acc[c], off);
    if (l == 0) {
#pragma unroll
        for (int c = 0; c < C_; ++c) out[b * C_ + c] = acc[c] + bp[c];
    }
}

extern "C" void kernel_launch(void* const* d_in, const int* in_sizes, int n_in,
                              void* d_out, int out_size, void* d_ws, size_t ws_size,
                              hipStream_t stream) {
    const float* x   = (const float*)d_in[0];   // [1024,128]
    const float* Whx = (const float*)d_in[1];   // [1,2048]
    const float* Whh = (const float*)d_in[2];   // [2048,2048]
    const float* bh  = (const float*)d_in[3];   // [2048]
    const float* Wph = (const float*)d_in[4];   // [2048,10]
    const float* bp  = (const float*)d_in[5];   // [1,10]
    float* out = (float*)d_out;                 // [1024,10]

    static bool attr_set = false;
    if (!attr_set) {
        hipFuncSetAttribute((const void*)rnn_persist,
                            hipFuncAttributeMaxDynamicSharedMemorySize, 147456);
        attr_set = true;
    }

    prep_w8<<<dim3(64, 64), 256, 0, stream>>>(Whh);
    rnn_init<<<(B_ * H_ / 4) / 256, 256, 0, stream>>>(x, Whx, bh);
    rnn_persist<<<256, 512, 147456, stream>>>(x, Whx, bh);
    rnn_proj<<<B_, 64, 0, stream>>>(Wph, bp, out);
}